// Round 3
// baseline (336.804 us; speedup 1.0000x reference)
//
#include <hip/hip_runtime.h>

typedef unsigned short u16;
typedef unsigned int u32;
typedef __attribute__((ext_vector_type(8))) short bh8;   // 8 x bf16 raw bits
typedef __attribute__((ext_vector_type(4))) float fx4;

#define QS 0.2550437194342803f   /* (1/sqrt(32)) * log2(e) */

__device__ __forceinline__ u16 f2bf(float f) {
    unsigned u = __float_as_uint(f);
    u += 0x7fffu + ((u >> 16) & 1u);   // round-to-nearest-even
    return (u16)(u >> 16);
}

// ------------------------------------------------------------------
// prep: convert x to bf16; transpose+convert weights; build fused QKV
// weight/bias with Q side pre-scaled by QS (softmax in exp2 domain)
// ------------------------------------------------------------------
__device__ __forceinline__ void trpose(const float* in, u16* out, int K, int N, int idx) {
    int n = idx / K, k = idx - n * K;
    out[idx] = f2bf(in[(size_t)k * N + n]);
}

__global__ __launch_bounds__(256) void prep_kernel(
    const float* x, const float* ew1, const float* ew2, const float* gw,
    const float* wq, const float* wk, const float* wv, const float* wo,
    const float* w1, const float* w2,
    const float* bq, const float* bk, const float* bv,
    u16* xb, u16* ew1t, u16* ew2t, u16* gwt,
    u16* wqkvt, float* bqkv, u16* wot, u16* w1t, u16* w2t)
{
    int gid = blockIdx.x * 256 + threadIdx.x;
    if (gid < 1048576) { xb[gid] = f2bf(x[gid]); return; } gid -= 1048576;
    if (gid < 32768) { trpose(ew1, ew1t, 256, 128, gid); return; } gid -= 32768;
    if (gid < 16384) { trpose(ew2, ew2t, 128, 128, gid); return; } gid -= 16384;
    if (gid < 16384) { trpose(gw,  gwt,  128, 128, gid); return; } gid -= 16384;
    if (gid < 98304) {   // wqkvt[l][384][128]
        int l = gid / 49152, rr = gid - l * 49152;
        int n = rr >> 7, kk = rr & 127;
        float v;
        if (n < 128)      v = wq[l * 16384 + kk * 128 + n] * QS;
        else if (n < 256) v = wk[l * 16384 + kk * 128 + (n - 128)];
        else              v = wv[l * 16384 + kk * 128 + (n - 256)];
        wqkvt[gid] = f2bf(v);
        return;
    } gid -= 98304;
    if (gid < 768) {     // bqkv[l][384]
        int l = gid / 384, n = gid - l * 384;
        float v;
        if (n < 128)      v = bq[l * 128 + n] * QS;
        else if (n < 256) v = bk[l * 128 + (n - 128)];
        else              v = bv[l * 128 + (n - 256)];
        bqkv[gid] = v;
        return;
    } gid -= 768;
    if (gid < 32768) { int l = gid >> 14, r = gid & 16383; trpose(wo + l*16384, wot + l*16384, 128, 128, r); return; } gid -= 32768;
    if (gid < 524288) { int l = gid / 262144, r = gid - l*262144; trpose(w1 + (size_t)l*262144, w1t + (size_t)l*262144, 128, 2048, r); return; } gid -= 524288;
    if (gid < 524288) { int l = gid / 262144, r = gid - l*262144; trpose(w2 + (size_t)l*262144, w2t + (size_t)l*262144, 2048, 128, r); return; }
}

// ------------------------------------------------------------------
// barrier-free bf16 MFMA GEMM: C[M,N] = A[M,K] @ Bt[N,K]^T (+bias, relu)
// 64x64 tile, 4 waves each 32x32; fragments loaded DIRECTLY from global
// (16B contiguous per lane; L1/L2 absorb intra-CU redundancy).
// Optional split-K: blockIdx.z covers [z*kchunk, (z+1)*kchunk), raw f32
// partial written to Cpart + z*M*N.
// ------------------------------------------------------------------
__global__ __launch_bounds__(256) void gemm_bf16(
    const u16* __restrict__ A, const u16* __restrict__ Bt,
    const float* __restrict__ bias,
    float* __restrict__ Cf, u16* __restrict__ Cb, float* __restrict__ Cpart,
    int M, int N, int K, int relu, int kchunk)
{
    const int m0 = blockIdx.x * 64, n0 = blockIdx.y * 64, z = blockIdx.z;
    const int tid = threadIdx.x;
    const int lane = tid & 63, w = tid >> 6;
    const int wm = (w >> 1) * 32, wn = (w & 1) * 32;
    const int l15 = lane & 15, l4 = lane >> 4;

    const u16* Ap0 = &A[(size_t)(m0 + wm + l15) * K + l4 * 8];
    const u16* Ap1 = Ap0 + (size_t)16 * K;
    const u16* Bp0 = &Bt[(size_t)(n0 + wn + l15) * K + l4 * 8];
    const u16* Bp1 = Bp0 + (size_t)16 * K;

    fx4 acc00 = {0,0,0,0}, acc01 = {0,0,0,0}, acc10 = {0,0,0,0}, acc11 = {0,0,0,0};

    const int k0 = z * kchunk, k1 = k0 + kchunk;
    #pragma unroll 4
    for (int kt = k0; kt < k1; kt += 32) {
        bh8 a0 = *(const bh8*)(Ap0 + kt);
        bh8 a1 = *(const bh8*)(Ap1 + kt);
        bh8 b0 = *(const bh8*)(Bp0 + kt);
        bh8 b1 = *(const bh8*)(Bp1 + kt);
        acc00 = __builtin_amdgcn_mfma_f32_16x16x32_bf16(a0, b0, acc00, 0, 0, 0);
        acc01 = __builtin_amdgcn_mfma_f32_16x16x32_bf16(a0, b1, acc01, 0, 0, 0);
        acc10 = __builtin_amdgcn_mfma_f32_16x16x32_bf16(a1, b0, acc10, 0, 0, 0);
        acc11 = __builtin_amdgcn_mfma_f32_16x16x32_bf16(a1, b1, acc11, 0, 0, 0);
    }

    fx4* accs[2][2] = {{&acc00, &acc01}, {&acc10, &acc11}};
    if (Cpart) {
        float* cp = Cpart + (size_t)z * M * N;
        for (int i = 0; i < 2; i++)
            for (int j = 0; j < 2; j++) {
                int colg = n0 + wn + j * 16 + l15;
                for (int r = 0; r < 4; r++) {
                    int rowg = m0 + wm + i * 16 + l4 * 4 + r;
                    cp[(size_t)rowg * N + colg] = (*accs[i][j])[r];
                }
            }
        return;
    }
    for (int i = 0; i < 2; i++)
        for (int j = 0; j < 2; j++) {
            int colg = n0 + wn + j * 16 + l15;
            float bvv = bias ? bias[colg] : 0.f;
            for (int r = 0; r < 4; r++) {
                int rowg = m0 + wm + i * 16 + l4 * 4 + r;
                float v = (*accs[i][j])[r] + bvv;
                if (relu) v = fmaxf(v, 0.f);
                if (Cf) Cf[(size_t)rowg * N + colg] = v;
                if (Cb) Cb[(size_t)rowg * N + colg] = f2bf(v);
            }
        }
}

// ------------------------------------------------------------------
// GAT attention-coefficient prep: a_src[n,h], a_dst[n,h]
// ------------------------------------------------------------------
__global__ __launch_bounds__(128) void gat_prep(
    const float* __restrict__ hh, const float* __restrict__ asrc,
    const float* __restrict__ adst, float* __restrict__ an_src,
    float* __restrict__ an_dst)
{
    int n = blockIdx.x, tid = threadIdx.x;
    int head = tid >> 6, c = tid & 63;
    float v = hh[n * 128 + tid];
    float ps = v * asrc[head * 64 + c];
    float pd = v * adst[head * 64 + c];
    for (int off = 32; off; off >>= 1) { ps += __shfl_down(ps, off); pd += __shfl_down(pd, off); }
    if (c == 0) { an_src[n * 2 + head] = ps; an_dst[n * 2 + head] = pd; }
}

// ------------------------------------------------------------------
// CSR build
// ------------------------------------------------------------------
__global__ void count_edges(const int* __restrict__ dst, int* counts, int E) {
    int i = blockIdx.x * 256 + threadIdx.x;
    if (i < E) atomicAdd(&counts[dst[i]], 1);
}

__global__ __launch_bounds__(1024) void scan_kernel(const int* __restrict__ counts,
                                                    int* row_start, int* cursor) {
    __shared__ int s[1024];
    int tid = threadIdx.x, b = tid * 4;
    int c0 = counts[b], c1 = counts[b+1], c2 = counts[b+2], c3 = counts[b+3];
    int sum = c0 + c1 + c2 + c3;
    s[tid] = sum;
    __syncthreads();
    for (int off = 1; off < 1024; off <<= 1) {
        int v = (tid >= off) ? s[tid - off] : 0;
        __syncthreads();
        s[tid] += v;
        __syncthreads();
    }
    int excl = s[tid] - sum;
    int r0 = excl, r1 = excl + c0, r2 = r1 + c1, r3 = r2 + c2;
    row_start[b] = r0; row_start[b+1] = r1; row_start[b+2] = r2; row_start[b+3] = r3;
    cursor[b] = r0; cursor[b+1] = r1; cursor[b+2] = r2; cursor[b+3] = r3;
    if (tid == 1023) row_start[4096] = s[1023];
}

__global__ void scatter_edges(const int* __restrict__ src, const int* __restrict__ dst,
                              int* cursor, int* csr_src, int E) {
    int i = blockIdx.x * 256 + threadIdx.x;
    if (i < E) { int pos = atomicAdd(&cursor[dst[i]], 1); csr_src[pos] = src[i]; }
}

// ------------------------------------------------------------------
// GAT aggregate: one block per destination node (segment softmax + agg)
// ------------------------------------------------------------------
__global__ __launch_bounds__(128) void gat_aggregate(
    const int* __restrict__ row_start, const int* __restrict__ csr_src,
    const float* __restrict__ an_src, const float* __restrict__ an_dst,
    const float* __restrict__ hh, const float* __restrict__ gbias,
    float* __restrict__ y32, u16* __restrict__ yb)
{
    int n = blockIdx.x, tid = threadIdx.x;
    int start = row_start[n], end = row_start[n + 1];
    float ad0 = an_dst[n * 2 + 0], ad1 = an_dst[n * 2 + 1];

    float mx0 = -1e30f, mx1 = -1e30f;
    for (int i = start + tid; i < end; i += 128) {
        int s = csr_src[i];
        float e0 = an_src[s * 2 + 0] + ad0; e0 = e0 > 0.f ? e0 : 0.2f * e0;
        float e1 = an_src[s * 2 + 1] + ad1; e1 = e1 > 0.f ? e1 : 0.2f * e1;
        mx0 = fmaxf(mx0, e0); mx1 = fmaxf(mx1, e1);
    }
    for (int off = 32; off; off >>= 1) { mx0 = fmaxf(mx0, __shfl_down(mx0, off)); mx1 = fmaxf(mx1, __shfl_down(mx1, off)); }
    __shared__ float sm[2][2];
    if ((tid & 63) == 0) { sm[tid >> 6][0] = mx0; sm[tid >> 6][1] = mx1; }
    __syncthreads();
    mx0 = fmaxf(sm[0][0], sm[1][0]); mx1 = fmaxf(sm[0][1], sm[1][1]);

    float s0 = 0.f, s1 = 0.f;
    for (int i = start + tid; i < end; i += 128) {
        int s = csr_src[i];
        float e0 = an_src[s * 2 + 0] + ad0; e0 = e0 > 0.f ? e0 : 0.2f * e0;
        float e1 = an_src[s * 2 + 1] + ad1; e1 = e1 > 0.f ? e1 : 0.2f * e1;
        s0 += __expf(e0 - mx0); s1 += __expf(e1 - mx1);
    }
    for (int off = 32; off; off >>= 1) { s0 += __shfl_down(s0, off); s1 += __shfl_down(s1, off); }
    __shared__ float ss[2][2];
    if ((tid & 63) == 0) { ss[tid >> 6][0] = s0; ss[tid >> 6][1] = s1; }
    __syncthreads();
    s0 = ss[0][0] + ss[1][0]; s1 = ss[0][1] + ss[1][1];

    int head = tid >> 6, c = tid & 63;
    float mx = head ? mx1 : mx0, dn = head ? s1 : s0, ad = head ? ad1 : ad0;
    float agg = 0.f;
    for (int i = start; i < end; i++) {
        int s = csr_src[i];
        float e = an_src[s * 2 + head] + ad; e = e > 0.f ? e : 0.2f * e;
        agg += (__expf(e - mx) / dn) * hh[(size_t)s * 128 + head * 64 + c];
    }
    float v = agg + gbias[tid];
    y32[(size_t)n * 128 + tid] = v;
    yb[(size_t)n * 128 + tid] = f2bf(v);
}

// ------------------------------------------------------------------
// transpose V (cols 256..383 of qkv [4096][384]) -> Vt [128][4096]
// ------------------------------------------------------------------
__global__ __launch_bounds__(256) void transpose_v(const u16* __restrict__ qkv, u16* __restrict__ vt) {
    int idx = blockIdx.x * 256 + threadIdx.x;   // over 128*4096
    int n = idx & 4095, hc = idx >> 12;
    vt[idx] = qkv[(size_t)n * 384 + 256 + hc];
}

// ------------------------------------------------------------------
// flash attention partial, barrier-free. grid (N/64, NH, 8 chunks).
// Swapped QK^T: S^T = mfma(K_frag, Q_frag) -> lane owns one q (=lane&15),
// 16 keys. Softmax per-lane + 2 shfl_xor. P^T staged wave-private in LDS
// as Ps[q][key]; K and V^T fragments loaded directly from global.
// ------------------------------------------------------------------
__global__ __launch_bounds__(256) void flash_attn_part(
    const u16* __restrict__ q, const u16* __restrict__ k,
    const u16* __restrict__ vt, float* __restrict__ po,
    float* __restrict__ pm, float* __restrict__ pl)
{
    __shared__ __align__(16) u16 Ps[4][16][72];
    const int q0 = blockIdx.x * 64, h = blockIdx.y, ch = blockIdx.z;
    const int tid = threadIdx.x;
    const int w = tid >> 6, lane = tid & 63, l15 = lane & 15, l4 = lane >> 4;

    bh8 qf = *(const bh8*)&q[(size_t)(q0 + w * 16 + l15) * 384 + h * 32 + l4 * 8];
    const u16* kbase = &k[(size_t)(ch * 512 + l15) * 384 + h * 32 + l4 * 8];
    const u16* vbase = &vt[(size_t)(h * 32 + l15) * 4096 + ch * 512 + l4 * 8];

    fx4 o0 = {0,0,0,0}, o1 = {0,0,0,0};
    float M = -1e30f, L = 0.f;

    #pragma unroll 2
    for (int ti = 0; ti < 8; ti++) {
        const u16* kp = kbase + (size_t)ti * 64 * 384;
        fx4 s[4];
        for (int sub = 0; sub < 4; sub++) {
            bh8 kf = *(const bh8*)(kp + (size_t)sub * 16 * 384);
            fx4 z = {0,0,0,0};
            s[sub] = __builtin_amdgcn_mfma_f32_16x16x32_bf16(kf, qf, z, 0, 0, 0);
        }
        // lane holds S^T[key = sub*16 + l4*4 + r][q = l15]
        float m = fmaxf(fmaxf(s[0][0], s[0][1]), fmaxf(s[0][2], s[0][3]));
        for (int sub = 1; sub < 4; sub++)
            m = fmaxf(m, fmaxf(fmaxf(s[sub][0], s[sub][1]), fmaxf(s[sub][2], s[sub][3])));
        m = fmaxf(m, __shfl_xor(m, 16));
        m = fmaxf(m, __shfl_xor(m, 32));
        float Mn = fmaxf(M, m);
        float f = __builtin_amdgcn_exp2f(M - Mn);
        M = Mn;
        o0 *= f; o1 *= f; L *= f;

        float lsum = 0.f;
        for (int sub = 0; sub < 4; sub++)
            for (int r = 0; r < 4; r++) {
                float pv = __builtin_amdgcn_exp2f(s[sub][r] - M);
                s[sub][r] = pv;
                lsum += pv;
            }
        lsum += __shfl_xor(lsum, 16);
        lsum += __shfl_xor(lsum, 32);
        L += lsum;

        // pack P^T (bf16 pairs) into Ps[w][q][key]; key = sub*16 + l4*4 + {0..3}
        for (int sub = 0; sub < 4; sub++) {
            u32 w0 = (u32)f2bf(s[sub][0]) | ((u32)f2bf(s[sub][1]) << 16);
            u32 w1 = (u32)f2bf(s[sub][2]) | ((u32)f2bf(s[sub][3]) << 16);
            *(u32*)&Ps[w][l15][sub * 16 + l4 * 4]     = w0;
            *(u32*)&Ps[w][l15][sub * 16 + l4 * 4 + 2] = w1;
        }

        // PV: O^T += V^T_chunk @ P^T_chunk (per 32-key chunk)
        const u16* vp = vbase + ti * 64;
        for (int kc = 0; kc < 2; kc++) {
            bh8 bf  = *(const bh8*)&Ps[w][l15][kc * 32 + l4 * 8];
            bh8 af0 = *(const bh8*)(vp + kc * 32);
            bh8 af1 = *(const bh8*)(vp + (size_t)16 * 4096 + kc * 32);
            o0 = __builtin_amdgcn_mfma_f32_16x16x32_bf16(af0, bf, o0, 0, 0, 0);
            o1 = __builtin_amdgcn_mfma_f32_16x16x32_bf16(af1, bf, o1, 0, 0, 0);
        }
    }
    // o0[r] = O^T[d = l4*4+r][q = l15], o1: d+16
    const int base = (blockIdx.x * 4 + h) * 8 + ch;
    const int qrow = w * 16 + l15;
    *(fx4*)&po[(size_t)(base * 64 + qrow) * 32 + l4 * 4]      = o0;
    *(fx4*)&po[(size_t)(base * 64 + qrow) * 32 + 16 + l4 * 4] = o1;
    if (l4 == 0) { pm[base * 64 + qrow] = M; pl[base * 64 + qrow] = L; }
}

// ------------------------------------------------------------------
// combine the 8 KV-chunk partials: out = (sum_i 2^(Mi-m*) Oi) / (sum_i 2^(Mi-m*) Li)
// grid (64, 4), 256 threads
// ------------------------------------------------------------------
__global__ __launch_bounds__(256) void attn_combine(
    const float* __restrict__ po, const float* __restrict__ pm,
    const float* __restrict__ pl, u16* __restrict__ out)
{
    int qb = blockIdx.x, h = blockIdx.y;
    int col = threadIdx.x & 31, r0 = threadIdx.x >> 5;
    int rb = (qb * 4 + h) * 8;
    for (int j = 0; j < 8; j++) {
        int row = r0 * 8 + j;
        float m = -1e30f;
        for (int c = 0; c < 8; c++) m = fmaxf(m, pm[(rb + c) * 64 + row]);
        float l = 0.f, o = 0.f;
        for (int c = 0; c < 8; c++) {
            float wgt = __builtin_amdgcn_exp2f(pm[(rb + c) * 64 + row] - m);
            l += wgt * pl[(rb + c) * 64 + row];
            o += wgt * po[(size_t)((rb + c) * 64 + row) * 32 + col];
        }
        out[(size_t)(qb * 64 + row) * 128 + h * 32 + col] = f2bf(o / l);
    }
}

// ------------------------------------------------------------------
// residual add + LayerNorm (128 channels), writes f32 + bf16
// ------------------------------------------------------------------
__global__ __launch_bounds__(128) void add_ln(
    const float* __restrict__ y, const float* __restrict__ delta,
    const float* __restrict__ g, const float* __restrict__ b,
    float* __restrict__ out32, u16* __restrict__ outb)
{
    int n = blockIdx.x, tid = threadIdx.x;
    float v = y[(size_t)n * 128 + tid] + delta[(size_t)n * 128 + tid];
    float sacc = v;
    for (int off = 32; off; off >>= 1) sacc += __shfl_down(sacc, off);
    __shared__ float sm[2], sv[2];
    if ((tid & 63) == 0) sm[tid >> 6] = sacc;
    __syncthreads();
    float mean = (sm[0] + sm[1]) * (1.f / 128.f);
    float d = v - mean;
    float qacc = d * d;
    for (int off = 32; off; off >>= 1) qacc += __shfl_down(qacc, off);
    if ((tid & 63) == 0) sv[tid >> 6] = qacc;
    __syncthreads();
    float var = (sv[0] + sv[1]) * (1.f / 128.f);
    float o = d * rsqrtf(var + 1e-5f) * g[tid] + b[tid];
    out32[(size_t)n * 128 + tid] = o;
    outb[(size_t)n * 128 + tid] = f2bf(o);
}

// ------------------------------------------------------------------
// residual add + sum of 8 split-K partials + bias + LayerNorm
// ------------------------------------------------------------------
__global__ __launch_bounds__(128) void add_ln8(
    const float* __restrict__ y, const float* __restrict__ part,
    const float* __restrict__ bias,
    const float* __restrict__ g, const float* __restrict__ b,
    float* __restrict__ out32, u16* __restrict__ outb)
{
    int n = blockIdx.x, tid = threadIdx.x;
    float v = y[(size_t)n * 128 + tid] + bias[tid];
    for (int z = 0; z < 8; z++) v += part[(size_t)z * 524288 + n * 128 + tid];
    float sacc = v;
    for (int off = 32; off; off >>= 1) sacc += __shfl_down(sacc, off);
    __shared__ float sm[2], sv[2];
    if ((tid & 63) == 0) sm[tid >> 6] = sacc;
    __syncthreads();
    float mean = (sm[0] + sm[1]) * (1.f / 128.f);
    float d = v - mean;
    float qacc = d * d;
    for (int off = 32; off; off >>= 1) qacc += __shfl_down(qacc, off);
    if ((tid & 63) == 0) sv[tid >> 6] = qacc;
    __syncthreads();
    float var = (sv[0] + sv[1]) * (1.f / 128.f);
    float o = d * rsqrtf(var + 1e-5f) * g[tid] + b[tid];
    out32[(size_t)n * 128 + tid] = o;
    outb[(size_t)n * 128 + tid] = f2bf(o);
}

// ------------------------------------------------------------------
extern "C" void kernel_launch(void* const* d_in, const int* in_sizes, int n_in,
                              void* d_out, int out_size, void* d_ws, size_t ws_size,
                              hipStream_t stream)
{
    const float* x     = (const float*)d_in[0];
    const int*   ei    = (const int*)  d_in[1];
    const float* ew1   = (const float*)d_in[2];
    const float* eb1   = (const float*)d_in[3];
    const float* ew2   = (const float*)d_in[4];
    const float* eb2   = (const float*)d_in[5];
    const float* gw    = (const float*)d_in[6];
    const float* gasrc = (const float*)d_in[7];
    const float* gadst = (const float*)d_in[8];
    const float* gbias = (const float*)d_in[9];
    const float* wq    = (const float*)d_in[10];
    const float* bq    = (const float*)d_in[11];
    const float* wk    = (const float*)d_in[12];
    const float* bk    = (const float*)d_in[13];
    const float* wv    = (const float*)d_in[14];
    const float* bv    = (const float*)d_in[15];
    const float* wo    = (const float*)d_in[16];
    const float* bo    = (const float*)d_in[17];
    const float* ln1g  = (const float*)d_in[18];
    const float* ln1b  = (const float*)d_in[19];
    const float* ln2g  = (const float*)d_in[20];
    const float* ln2b  = (const float*)d_in[21];
    const float* w1    = (const float*)d_in[22];
    const float* b1    = (const float*)d_in[23];
    const float* w2    = (const float*)d_in[24];
    const float* b2    = (const float*)d_in[25];

    const int E = in_sizes[1] / 2;
    const int* esrc = ei;
    const int* edst = ei + E;

    char* p = (char*)d_ws;
    auto alloc = [&](size_t bytes) -> void* {
        void* r = (void*)p;
        p += (bytes + 255) & ~(size_t)255;
        return r;
    };
    u16* xb    = (u16*)alloc(4096 * 256 * 2);
    u16* ew1t  = (u16*)alloc(128 * 256 * 2);
    u16* ew2t  = (u16*)alloc(128 * 128 * 2);
    u16* gwt   = (u16*)alloc(128 * 128 * 2);
    u16* wqkvt = (u16*)alloc(2 * 384 * 128 * 2);
    float* bqkv = (float*)alloc(2 * 384 * 4);
    u16* wot   = (u16*)alloc(2 * 128 * 128 * 2);
    u16* w1t   = (u16*)alloc(2 * 2048 * 128 * 2);
    u16* w2t   = (u16*)alloc(2 * 128 * 2048 * 2);
    u16* h1b   = (u16*)alloc(4096 * 128 * 2);
    u16* hb    = (u16*)alloc(4096 * 128 * 2);
    float* hh  = (float*)alloc(4096 * 128 * 4);
    float* ansrc = (float*)alloc(4096 * 2 * 4);
    float* andst = (float*)alloc(4096 * 2 * 4);
    int* counts    = (int*)alloc(4096 * 4);
    int* row_start = (int*)alloc(4097 * 4);
    int* cursor    = (int*)alloc(4096 * 4);
    int* csr_src   = (int*)alloc((size_t)E * 4);
    float* y32 = (float*)alloc(4096 * 128 * 4);
    u16* yb    = (u16*)alloc(4096 * 128 * 2);
    u16* qkvb  = (u16*)alloc((size_t)4096 * 384 * 2);
    u16* vtb   = (u16*)alloc(4096 * 128 * 2);
    u16* attnb = (u16*)alloc(4096 * 128 * 2);
    float* po  = (float*)alloc((size_t)64 * 4 * 8 * 64 * 32 * 4);
    float* pm  = (float*)alloc(64 * 4 * 8 * 64 * 4);
    float* pl  = (float*)alloc(64 * 4 * 8 * 64 * 4);
    float* proj32 = (float*)alloc(4096 * 128 * 4);
    u16* ff1b  = (u16*)alloc((size_t)4096 * 2048 * 2);
    float* ff2part = (float*)alloc((size_t)8 * 4096 * 128 * 4);

    // ---- prep (x + all weights) ----
    prep_kernel<<<8963, 256, 0, stream>>>(x, ew1, ew2, gw, wq, wk, wv, wo, w1, w2,
                                          bq, bk, bv,
                                          xb, ew1t, ew2t, gwt, wqkvt, bqkv, wot, w1t, w2t);

    // ---- encoder MLP ----
    gemm_bf16<<<dim3(64, 2), 256, 0, stream>>>(xb, ew1t, eb1, nullptr, h1b, nullptr, 4096, 128, 256, 1, 256);
    gemm_bf16<<<dim3(64, 2), 256, 0, stream>>>(h1b, ew2t, eb2, nullptr, hb, nullptr, 4096, 128, 128, 0, 128);

    // ---- GAT ----
    gemm_bf16<<<dim3(64, 2), 256, 0, stream>>>(hb, gwt, nullptr, hh, nullptr, nullptr, 4096, 128, 128, 0, 128);
    gat_prep<<<4096, 128, 0, stream>>>(hh, gasrc, gadst, ansrc, andst);
    hipMemsetAsync(counts, 0, 4096 * sizeof(int), stream);
    count_edges<<<(E + 255) / 256, 256, 0, stream>>>(edst, counts, E);
    scan_kernel<<<1, 1024, 0, stream>>>(counts, row_start, cursor);
    scatter_edges<<<(E + 255) / 256, 256, 0, stream>>>(esrc, edst, cursor, csr_src, E);
    gat_aggregate<<<4096, 128, 0, stream>>>(row_start, csr_src, ansrc, andst, hh, gbias, y32, yb);

    // ---- transformer layers ----
    for (int l = 0; l < 2; l++) {
        gemm_bf16<<<dim3(64, 6), 256, 0, stream>>>(yb, wqkvt + l * 49152, bqkv + l * 384, nullptr, qkvb, nullptr, 4096, 384, 128, 0, 128);
        transpose_v<<<2048, 256, 0, stream>>>(qkvb, vtb);
        flash_attn_part<<<dim3(64, 4, 8), 256, 0, stream>>>(qkvb, qkvb + 128, vtb, po, pm, pl);
        attn_combine<<<dim3(64, 4), 256, 0, stream>>>(po, pm, pl, attnb);
        gemm_bf16<<<dim3(64, 2), 256, 0, stream>>>(attnb, wot + l * 16384, bo + l * 128, proj32, nullptr, nullptr, 4096, 128, 128, 0, 128);
        add_ln<<<4096, 128, 0, stream>>>(y32, proj32, ln1g + l * 128, ln1b + l * 128, y32, yb);
        gemm_bf16<<<dim3(64, 32), 256, 0, stream>>>(yb, w1t + (size_t)l * 262144, b1 + l * 2048, nullptr, ff1b, nullptr, 4096, 2048, 128, 1, 128);
        gemm_bf16<<<dim3(64, 2, 8), 256, 0, stream>>>(ff1b, w2t + (size_t)l * 262144, nullptr, nullptr, nullptr, ff2part, 4096, 128, 2048, 0, 256);
        float* outp = (l == 1) ? (float*)d_out : y32;
        add_ln8<<<4096, 128, 0, stream>>>(y32, ff2part, b2 + l * 128, ln2g + l * 128, ln2b + l * 128, outp, yb);
    }
}

// Round 4
// 216.311 us; speedup vs baseline: 1.5570x; 1.5570x over previous
//
#include <hip/hip_runtime.h>

typedef unsigned short u16;
typedef unsigned int u32;
typedef __attribute__((ext_vector_type(8))) short bh8;   // 8 x bf16 raw bits
typedef __attribute__((ext_vector_type(4))) float fx4;
typedef __attribute__((ext_vector_type(4))) short s4;

#define QS 0.2550437194342803f   /* (1/sqrt(32)) * log2(e) */

__device__ __forceinline__ u16 f2bf(float f) {
    unsigned u = __float_as_uint(f);
    u += 0x7fffu + ((u >> 16) & 1u);   // round-to-nearest-even
    return (u16)(u >> 16);
}

// ------------------------------------------------------------------
// prep: x -> bf16 (vectorized copy); all weights transposed via tiled
// 64x64 LDS transpose (coalesced global reads AND writes); fused QKV
// weight/bias with Q side pre-scaled by QS (softmax in exp2 domain).
// grid = 128 (x) + 1 (bias) + 304 transpose tiles = 433 blocks
// ------------------------------------------------------------------
__global__ __launch_bounds__(256) void prep_kernel(
    const float* x, const float* ew1, const float* ew2, const float* gw,
    const float* wq, const float* wk, const float* wv, const float* wo,
    const float* w1, const float* w2,
    const float* bq, const float* bk, const float* bv,
    u16* xb, u16* ew1t, u16* ew2t, u16* gwt,
    u16* wqkvt, float* bqkv, u16* wot, u16* w1t, u16* w2t)
{
    __shared__ u16 tile[64 * 65];
    int bid = blockIdx.x;
    const int t = threadIdx.x;

    if (bid < 128) {   // x convert: 1M floats
        const float4* x4 = (const float4*)x;
        s4* o4 = (s4*)xb;
        #pragma unroll
        for (int i = 0; i < 8; i++) {
            int fi = bid * 2048 + i * 256 + t;
            float4 v = x4[fi];
            s4 o = { (short)f2bf(v.x), (short)f2bf(v.y), (short)f2bf(v.z), (short)f2bf(v.w) };
            o4[fi] = o;
        }
        return;
    }
    bid -= 128;
    if (bid < 1) {     // bqkv [2][384]
        for (int idx = t; idx < 768; idx += 256) {
            int l = idx / 384, n = idx % 384;
            float v;
            if (n < 128)      v = bq[l * 128 + n] * QS;
            else if (n < 256) v = bk[l * 128 + n - 128];
            else              v = bv[l * 128 + n - 256];
            bqkv[idx] = v;
        }
        return;
    }
    bid -= 1;

    const float* src; u16* dst; int R, C, tr, tc; float sc = 1.f;
    if (bid < 8)            { src = ew1; dst = ew1t; R = 256; C = 128; tr = bid >> 1; tc = bid & 1; }
    else if ((bid -= 8) < 4)  { src = ew2; dst = ew2t; R = 128; C = 128; tr = bid >> 1; tc = bid & 1; }
    else if ((bid -= 4) < 4)  { src = gw;  dst = gwt;  R = 128; C = 128; tr = bid >> 1; tc = bid & 1; }
    else if ((bid -= 4) < 24) {
        int l = bid / 12, r2 = bid % 12, which = r2 >> 2, i = r2 & 3;
        R = 128; C = 128; tr = i >> 1; tc = i & 1;
        if (which == 0)      { src = wq + l * 16384; dst = wqkvt + l * 49152;         sc = QS; }
        else if (which == 1) { src = wk + l * 16384; dst = wqkvt + l * 49152 + 16384; }
        else                 { src = wv + l * 16384; dst = wqkvt + l * 49152 + 32768; }
    }
    else if ((bid -= 24) < 8)   { int l = bid >> 2, i = bid & 3;  src = wo + l * 16384; dst = wot + l * 16384; R = 128; C = 128; tr = i >> 1; tc = i & 1; }
    else if ((bid -= 8) < 128)  { int l = bid >> 6, i = bid & 63; src = w1 + (size_t)l * 262144; dst = w1t + (size_t)l * 262144; R = 128;  C = 2048; tr = i & 1;  tc = i >> 1; }
    else { bid -= 128;            int l = bid >> 6, i = bid & 63; src = w2 + (size_t)l * 262144; dst = w2t + (size_t)l * 262144; R = 2048; C = 128;  tr = i >> 1; tc = i & 1; }

    // transpose 64x64 tile: dst[(tc*64+c)*R + tr*64 + r] = src[(tr*64+r)*C + tc*64 + c]
    const int r = t >> 2, cs = (t & 3) * 16;
    const float* sp = src + (size_t)(tr * 64 + r) * C + tc * 64 + cs;
    #pragma unroll
    for (int j = 0; j < 16; j++) tile[r * 65 + cs + j] = f2bf(sp[j] * sc);
    __syncthreads();
    u16* dp = dst + (size_t)(tc * 64 + r) * R + tr * 64 + cs;
    #pragma unroll
    for (int j = 0; j < 16; j++) dp[j] = tile[(cs + j) * 65 + r];
}

// ------------------------------------------------------------------
// staged bf16 MFMA GEMM: C[M,N] = A[M,K] @ Bt[N,K]^T (+bias, relu)
// 64x64 tile, 4 waves each 32x32. Double-buffered LDS, ONE barrier per
// K-step: loads for step t+1 issue right after the barrier (nothing
// outstanding at the barrier), compute covers latency, ds_write at end.
// split-K via blockIdx.z/kchunk -> f32 partial to Cpart.
// Cvt: for the QKV GEMM, cols >=256 (V) are written TRANSPOSED to Cvt
// [128][4096] instead of Cb (which uses pitch ldc).
// ------------------------------------------------------------------
__global__ __launch_bounds__(256) void gemm_bf16(
    const u16* __restrict__ A, const u16* __restrict__ Bt,
    const float* __restrict__ bias,
    float* __restrict__ Cf, u16* __restrict__ Cb, float* __restrict__ Cpart,
    u16* __restrict__ Cvt,
    int M, int N, int K, int relu, int kchunk, int ldc)
{
    __shared__ __align__(16) u16 As[2][64][40];
    __shared__ __align__(16) u16 Bs[2][64][40];
    const int m0 = blockIdx.x * 64, n0 = blockIdx.y * 64, z = blockIdx.z;
    const int tid = threadIdx.x;
    const int lane = tid & 63, w = tid >> 6;
    const int wm = (w >> 1) * 32, wn = (w & 1) * 32;
    const int l15 = lane & 15, l4 = lane >> 4;
    const int srow = tid >> 2, skq = (tid & 3) * 8;
    const int k0 = z * kchunk;

    const u16* Ap = A + (size_t)(m0 + srow) * K + k0 + skq;
    const u16* Bp = Bt + (size_t)(n0 + srow) * K + k0 + skq;

    fx4 acc00 = {0,0,0,0}, acc01 = {0,0,0,0}, acc10 = {0,0,0,0}, acc11 = {0,0,0,0};

    // prologue: stage step 0
    *(int4*)&As[0][srow][skq] = *(const int4*)Ap;
    *(int4*)&Bs[0][srow][skq] = *(const int4*)Bp;

    const int niter = kchunk >> 5;
    for (int it = 0; it < niter; it++) {
        const int cur = it & 1;
        int4 ar, br;
        __syncthreads();
        if (it + 1 < niter) {
            ar = *(const int4*)(Ap + (it + 1) * 32);
            br = *(const int4*)(Bp + (it + 1) * 32);
        }
        bh8 a0 = *(const bh8*)&As[cur][wm + l15][l4 * 8];
        bh8 a1 = *(const bh8*)&As[cur][wm + 16 + l15][l4 * 8];
        bh8 b0 = *(const bh8*)&Bs[cur][wn + l15][l4 * 8];
        bh8 b1 = *(const bh8*)&Bs[cur][wn + 16 + l15][l4 * 8];
        acc00 = __builtin_amdgcn_mfma_f32_16x16x32_bf16(a0, b0, acc00, 0, 0, 0);
        acc01 = __builtin_amdgcn_mfma_f32_16x16x32_bf16(a0, b1, acc01, 0, 0, 0);
        acc10 = __builtin_amdgcn_mfma_f32_16x16x32_bf16(a1, b0, acc10, 0, 0, 0);
        acc11 = __builtin_amdgcn_mfma_f32_16x16x32_bf16(a1, b1, acc11, 0, 0, 0);
        if (it + 1 < niter) {
            *(int4*)&As[cur ^ 1][srow][skq] = ar;
            *(int4*)&Bs[cur ^ 1][srow][skq] = br;
        }
    }

    fx4* accs[2][2] = {{&acc00, &acc01}, {&acc10, &acc11}};
    #pragma unroll
    for (int i = 0; i < 2; i++)
        #pragma unroll
        for (int j = 0; j < 2; j++) {
            int colg = n0 + wn + j * 16 + l15;
            int rowb = m0 + wm + i * 16 + l4 * 4;
            if (Cpart) {
                float* cp = Cpart + (size_t)z * M * N;
                #pragma unroll
                for (int r = 0; r < 4; r++)
                    cp[(size_t)(rowb + r) * N + colg] = (*accs[i][j])[r];
                continue;
            }
            float bvv = bias ? bias[colg] : 0.f;
            float vals[4];
            #pragma unroll
            for (int r = 0; r < 4; r++) {
                float v = (*accs[i][j])[r] + bvv;
                vals[r] = relu ? fmaxf(v, 0.f) : v;
            }
            if (Cvt && colg >= 256) {
                s4 pk = { (short)f2bf(vals[0]), (short)f2bf(vals[1]),
                          (short)f2bf(vals[2]), (short)f2bf(vals[3]) };
                *(s4*)&Cvt[(size_t)(colg - 256) * 4096 + rowb] = pk;
            } else {
                #pragma unroll
                for (int r = 0; r < 4; r++) {
                    if (Cf) Cf[(size_t)(rowb + r) * ldc + colg] = vals[r];
                    if (Cb) Cb[(size_t)(rowb + r) * ldc + colg] = f2bf(vals[r]);
                }
            }
        }
}

// ------------------------------------------------------------------
// GAT attention-coefficient prep: a_src[n,h], a_dst[n,h]
// ------------------------------------------------------------------
__global__ __launch_bounds__(128) void gat_prep(
    const float* __restrict__ hh, const float* __restrict__ asrc,
    const float* __restrict__ adst, float* __restrict__ an_src,
    float* __restrict__ an_dst)
{
    int n = blockIdx.x, tid = threadIdx.x;
    int head = tid >> 6, c = tid & 63;
    float v = hh[n * 128 + tid];
    float ps = v * asrc[head * 64 + c];
    float pd = v * adst[head * 64 + c];
    for (int off = 32; off; off >>= 1) { ps += __shfl_down(ps, off); pd += __shfl_down(pd, off); }
    if (c == 0) { an_src[n * 2 + head] = ps; an_dst[n * 2 + head] = pd; }
}

// ------------------------------------------------------------------
// CSR build
// ------------------------------------------------------------------
__global__ void count_edges(const int* __restrict__ dst, int* counts, int E) {
    int i = blockIdx.x * 256 + threadIdx.x;
    if (i < E) atomicAdd(&counts[dst[i]], 1);
}

__global__ __launch_bounds__(1024) void scan_kernel(const int* __restrict__ counts,
                                                    int* row_start, int* cursor) {
    __shared__ int s[1024];
    int tid = threadIdx.x, b = tid * 4;
    int c0 = counts[b], c1 = counts[b+1], c2 = counts[b+2], c3 = counts[b+3];
    int sum = c0 + c1 + c2 + c3;
    s[tid] = sum;
    __syncthreads();
    for (int off = 1; off < 1024; off <<= 1) {
        int v = (tid >= off) ? s[tid - off] : 0;
        __syncthreads();
        s[tid] += v;
        __syncthreads();
    }
    int excl = s[tid] - sum;
    int r0 = excl, r1 = excl + c0, r2 = r1 + c1, r3 = r2 + c2;
    row_start[b] = r0; row_start[b+1] = r1; row_start[b+2] = r2; row_start[b+3] = r3;
    cursor[b] = r0; cursor[b+1] = r1; cursor[b+2] = r2; cursor[b+3] = r3;
    if (tid == 1023) row_start[4096] = s[1023];
}

__global__ void scatter_edges(const int* __restrict__ src, const int* __restrict__ dst,
                              int* cursor, int* csr_src, int E) {
    int i = blockIdx.x * 256 + threadIdx.x;
    if (i < E) { int pos = atomicAdd(&cursor[dst[i]], 1); csr_src[pos] = src[i]; }
}

// ------------------------------------------------------------------
// GAT aggregate: one block per destination node (segment softmax + agg)
// ------------------------------------------------------------------
__global__ __launch_bounds__(128) void gat_aggregate(
    const int* __restrict__ row_start, const int* __restrict__ csr_src,
    const float* __restrict__ an_src, const float* __restrict__ an_dst,
    const float* __restrict__ hh, const float* __restrict__ gbias,
    float* __restrict__ y32, u16* __restrict__ yb)
{
    int n = blockIdx.x, tid = threadIdx.x;
    int start = row_start[n], end = row_start[n + 1];
    float ad0 = an_dst[n * 2 + 0], ad1 = an_dst[n * 2 + 1];

    float mx0 = -1e30f, mx1 = -1e30f;
    for (int i = start + tid; i < end; i += 128) {
        int s = csr_src[i];
        float e0 = an_src[s * 2 + 0] + ad0; e0 = e0 > 0.f ? e0 : 0.2f * e0;
        float e1 = an_src[s * 2 + 1] + ad1; e1 = e1 > 0.f ? e1 : 0.2f * e1;
        mx0 = fmaxf(mx0, e0); mx1 = fmaxf(mx1, e1);
    }
    for (int off = 32; off; off >>= 1) { mx0 = fmaxf(mx0, __shfl_down(mx0, off)); mx1 = fmaxf(mx1, __shfl_down(mx1, off)); }
    __shared__ float sm[2][2];
    if ((tid & 63) == 0) { sm[tid >> 6][0] = mx0; sm[tid >> 6][1] = mx1; }
    __syncthreads();
    mx0 = fmaxf(sm[0][0], sm[1][0]); mx1 = fmaxf(sm[0][1], sm[1][1]);

    float s0 = 0.f, s1 = 0.f;
    for (int i = start + tid; i < end; i += 128) {
        int s = csr_src[i];
        float e0 = an_src[s * 2 + 0] + ad0; e0 = e0 > 0.f ? e0 : 0.2f * e0;
        float e1 = an_src[s * 2 + 1] + ad1; e1 = e1 > 0.f ? e1 : 0.2f * e1;
        s0 += __expf(e0 - mx0); s1 += __expf(e1 - mx1);
    }
    for (int off = 32; off; off >>= 1) { s0 += __shfl_down(s0, off); s1 += __shfl_down(s1, off); }
    __shared__ float ss[2][2];
    if ((tid & 63) == 0) { ss[tid >> 6][0] = s0; ss[tid >> 6][1] = s1; }
    __syncthreads();
    s0 = ss[0][0] + ss[1][0]; s1 = ss[0][1] + ss[1][1];

    int head = tid >> 6, c = tid & 63;
    float mx = head ? mx1 : mx0, dn = head ? s1 : s0, ad = head ? ad1 : ad0;
    float agg = 0.f;
    for (int i = start; i < end; i++) {
        int s = csr_src[i];
        float e = an_src[s * 2 + head] + ad; e = e > 0.f ? e : 0.2f * e;
        agg += (__expf(e - mx) / dn) * hh[(size_t)s * 128 + head * 64 + c];
    }
    float v = agg + gbias[tid];
    y32[(size_t)n * 128 + tid] = v;
    yb[(size_t)n * 128 + tid] = f2bf(v);
}

// ------------------------------------------------------------------
// flash attention partial: grid (N/64, NH, 8). LDS-staged K/V tiles
// (double-buffered, ONE barrier per tile, loads issued post-barrier so
// nothing is outstanding at the barrier drain). Swapped QK^T:
// S^T = mfma(K,Q) -> lane owns q=lane&15; softmax in-register + 2 shfl.
// q pre-scaled by QS (exp2 domain). q/k pitch 256 (Q,K halves of qkvb).
// ------------------------------------------------------------------
__global__ __launch_bounds__(256) void flash_attn_part(
    const u16* __restrict__ q, const u16* __restrict__ k,
    const u16* __restrict__ vt, float* __restrict__ po,
    float* __restrict__ pm, float* __restrict__ pl)
{
    __shared__ __align__(16) u16 Kb[2][64][40];
    __shared__ __align__(16) u16 Vb[2][32][72];
    __shared__ __align__(16) u16 Ps[4][16][72];
    const int q0 = blockIdx.x * 64, h = blockIdx.y, ch = blockIdx.z;
    const int tid = threadIdx.x;
    const int w = tid >> 6, lane = tid & 63, l15 = lane & 15, l4 = lane >> 4;

    bh8 qf = *(const bh8*)&q[(size_t)(q0 + w * 16 + l15) * 256 + h * 32 + l4 * 8];

    const int skey = tid >> 2, sds = (tid & 3) * 8;   // K staging: 64 keys x 32 d
    const int svd = tid >> 3, svk = (tid & 7) * 8;    // V staging: 32 d x 64 keys
    const u16* kgp = &k[(size_t)(ch * 512 + skey) * 256 + h * 32 + sds];
    const u16* vgp = &vt[(size_t)(h * 32 + svd) * 4096 + ch * 512 + svk];

    fx4 o0 = {0,0,0,0}, o1 = {0,0,0,0};
    float M = -1e30f, L = 0.f;

    // prologue: stage tile 0
    *(int4*)&Kb[0][skey][sds] = *(const int4*)kgp;
    *(int4*)&Vb[0][svd][svk] = *(const int4*)vgp;

    for (int ti = 0; ti < 8; ti++) {
        const int cur = ti & 1;
        int4 kr, vr;
        __syncthreads();
        if (ti < 7) {   // issue next-tile loads AFTER barrier; compute hides latency
            kr = *(const int4*)(kgp + (size_t)(ti + 1) * 64 * 256);
            vr = *(const int4*)(vgp + (ti + 1) * 64);
        }

        fx4 s[4];
        #pragma unroll
        for (int sub = 0; sub < 4; sub++) {
            bh8 kf = *(const bh8*)&Kb[cur][sub * 16 + l15][l4 * 8];
            fx4 z = {0,0,0,0};
            s[sub] = __builtin_amdgcn_mfma_f32_16x16x32_bf16(kf, qf, z, 0, 0, 0);
        }
        // lane holds S^T[key = sub*16 + l4*4 + r][q = l15]
        float m = fmaxf(fmaxf(s[0][0], s[0][1]), fmaxf(s[0][2], s[0][3]));
        #pragma unroll
        for (int sub = 1; sub < 4; sub++)
            m = fmaxf(m, fmaxf(fmaxf(s[sub][0], s[sub][1]), fmaxf(s[sub][2], s[sub][3])));
        m = fmaxf(m, __shfl_xor(m, 16));
        m = fmaxf(m, __shfl_xor(m, 32));
        float Mn = fmaxf(M, m);
        float f = __builtin_amdgcn_exp2f(M - Mn);
        M = Mn;
        o0 *= f; o1 *= f; L *= f;

        float lsum = 0.f;
        #pragma unroll
        for (int sub = 0; sub < 4; sub++)
            #pragma unroll
            for (int r = 0; r < 4; r++) {
                float pv = __builtin_amdgcn_exp2f(s[sub][r] - M);
                s[sub][r] = pv;
                lsum += pv;
            }
        lsum += __shfl_xor(lsum, 16);
        lsum += __shfl_xor(lsum, 32);
        L += lsum;

        // pack P^T into Ps[w][q][key] (wave-private; DS in-order per wave)
        #pragma unroll
        for (int sub = 0; sub < 4; sub++) {
            u32 w0 = (u32)f2bf(s[sub][0]) | ((u32)f2bf(s[sub][1]) << 16);
            u32 w1 = (u32)f2bf(s[sub][2]) | ((u32)f2bf(s[sub][3]) << 16);
            *(u32*)&Ps[w][l15][sub * 16 + l4 * 4]     = w0;
            *(u32*)&Ps[w][l15][sub * 16 + l4 * 4 + 2] = w1;
        }

        // PV: O^T += V^T @ P^T
        #pragma unroll
        for (int kc = 0; kc < 2; kc++) {
            bh8 bf  = *(const bh8*)&Ps[w][l15][kc * 32 + l4 * 8];
            bh8 af0 = *(const bh8*)&Vb[cur][l15][kc * 32 + l4 * 8];
            bh8 af1 = *(const bh8*)&Vb[cur][16 + l15][kc * 32 + l4 * 8];
            o0 = __builtin_amdgcn_mfma_f32_16x16x32_bf16(af0, bf, o0, 0, 0, 0);
            o1 = __builtin_amdgcn_mfma_f32_16x16x32_bf16(af1, bf, o1, 0, 0, 0);
        }

        if (ti < 7) {   // write next tile (vmcnt waits land here, after compute)
            *(int4*)&Kb[cur ^ 1][skey][sds] = kr;
            *(int4*)&Vb[cur ^ 1][svd][svk] = vr;
        }
    }
    // o0[r] = O^T[d = l4*4+r][q = l15], o1: d+16
    const int base = (blockIdx.x * 4 + h) * 8 + ch;
    const int qrow = w * 16 + l15;
    *(fx4*)&po[(size_t)(base * 64 + qrow) * 32 + l4 * 4]      = o0;
    *(fx4*)&po[(size_t)(base * 64 + qrow) * 32 + 16 + l4 * 4] = o1;
    if (l4 == 0) { pm[base * 64 + qrow] = M; pl[base * 64 + qrow] = L; }
}

// ------------------------------------------------------------------
// combine the 8 KV-chunk partials
// ------------------------------------------------------------------
__global__ __launch_bounds__(256) void attn_combine(
    const float* __restrict__ po, const float* __restrict__ pm,
    const float* __restrict__ pl, u16* __restrict__ out)
{
    int qb = blockIdx.x, h = blockIdx.y;
    int col = threadIdx.x & 31, r0 = threadIdx.x >> 5;
    int rb = (qb * 4 + h) * 8;
    for (int j = 0; j < 8; j++) {
        int row = r0 * 8 + j;
        float m = -1e30f;
        for (int c = 0; c < 8; c++) m = fmaxf(m, pm[(rb + c) * 64 + row]);
        float l = 0.f, o = 0.f;
        for (int c = 0; c < 8; c++) {
            float wgt = __builtin_amdgcn_exp2f(pm[(rb + c) * 64 + row] - m);
            l += wgt * pl[(rb + c) * 64 + row];
            o += wgt * po[(size_t)((rb + c) * 64 + row) * 32 + col];
        }
        out[(size_t)(qb * 64 + row) * 128 + h * 32 + col] = f2bf(o / l);
    }
}

// ------------------------------------------------------------------
// residual add + LayerNorm (128 channels), writes f32 + bf16
// ------------------------------------------------------------------
__global__ __launch_bounds__(128) void add_ln(
    const float* __restrict__ y, const float* __restrict__ delta,
    const float* __restrict__ g, const float* __restrict__ b,
    float* __restrict__ out32, u16* __restrict__ outb)
{
    int n = blockIdx.x, tid = threadIdx.x;
    float v = y[(size_t)n * 128 + tid] + delta[(size_t)n * 128 + tid];
    float sacc = v;
    for (int off = 32; off; off >>= 1) sacc += __shfl_down(sacc, off);
    __shared__ float sm[2], sv[2];
    if ((tid & 63) == 0) sm[tid >> 6] = sacc;
    __syncthreads();
    float mean = (sm[0] + sm[1]) * (1.f / 128.f);
    float d = v - mean;
    float qacc = d * d;
    for (int off = 32; off; off >>= 1) qacc += __shfl_down(qacc, off);
    if ((tid & 63) == 0) sv[tid >> 6] = qacc;
    __syncthreads();
    float var = (sv[0] + sv[1]) * (1.f / 128.f);
    float o = d * rsqrtf(var + 1e-5f) * g[tid] + b[tid];
    out32[(size_t)n * 128 + tid] = o;
    outb[(size_t)n * 128 + tid] = f2bf(o);
}

// ------------------------------------------------------------------
// residual add + sum of 8 split-K partials + bias + LayerNorm
// ------------------------------------------------------------------
__global__ __launch_bounds__(128) void add_ln8(
    const float* __restrict__ y, const float* __restrict__ part,
    const float* __restrict__ bias,
    const float* __restrict__ g, const float* __restrict__ b,
    float* __restrict__ out32, u16* __restrict__ outb)
{
    int n = blockIdx.x, tid = threadIdx.x;
    float v = y[(size_t)n * 128 + tid] + bias[tid];
    for (int z = 0; z < 8; z++) v += part[(size_t)z * 524288 + n * 128 + tid];
    float sacc = v;
    for (int off = 32; off; off >>= 1) sacc += __shfl_down(sacc, off);
    __shared__ float sm[2], sv[2];
    if ((tid & 63) == 0) sm[tid >> 6] = sacc;
    __syncthreads();
    float mean = (sm[0] + sm[1]) * (1.f / 128.f);
    float d = v - mean;
    float qacc = d * d;
    for (int off = 32; off; off >>= 1) qacc += __shfl_down(qacc, off);
    if ((tid & 63) == 0) sv[tid >> 6] = qacc;
    __syncthreads();
    float var = (sv[0] + sv[1]) * (1.f / 128.f);
    float o = d * rsqrtf(var + 1e-5f) * g[tid] + b[tid];
    out32[(size_t)n * 128 + tid] = o;
    outb[(size_t)n * 128 + tid] = f2bf(o);
}

// ------------------------------------------------------------------
extern "C" void kernel_launch(void* const* d_in, const int* in_sizes, int n_in,
                              void* d_out, int out_size, void* d_ws, size_t ws_size,
                              hipStream_t stream)
{
    const float* x     = (const float*)d_in[0];
    const int*   ei    = (const int*)  d_in[1];
    const float* ew1   = (const float*)d_in[2];
    const float* eb1   = (const float*)d_in[3];
    const float* ew2   = (const float*)d_in[4];
    const float* eb2   = (const float*)d_in[5];
    const float* gw    = (const float*)d_in[6];
    const float* gasrc = (const float*)d_in[7];
    const float* gadst = (const float*)d_in[8];
    const float* gbias = (const float*)d_in[9];
    const float* wq    = (const float*)d_in[10];
    const float* bq    = (const float*)d_in[11];
    const float* wk    = (const float*)d_in[12];
    const float* bk    = (const float*)d_in[13];
    const float* wv    = (const float*)d_in[14];
    const float* bv    = (const float*)d_in[15];
    const float* wo    = (const float*)d_in[16];
    const float* bo    = (const float*)d_in[17];
    const float* ln1g  = (const float*)d_in[18];
    const float* ln1b  = (const float*)d_in[19];
    const float* ln2g  = (const float*)d_in[20];
    const float* ln2b  = (const float*)d_in[21];
    const float* w1    = (const float*)d_in[22];
    const float* b1    = (const float*)d_in[23];
    const float* w2    = (const float*)d_in[24];
    const float* b2    = (const float*)d_in[25];

    const int E = in_sizes[1] / 2;
    const int* esrc = ei;
    const int* edst = ei + E;

    char* p = (char*)d_ws;
    auto alloc = [&](size_t bytes) -> void* {
        void* r = (void*)p;
        p += (bytes + 255) & ~(size_t)255;
        return r;
    };
    u16* xb    = (u16*)alloc(4096 * 256 * 2);
    u16* ew1t  = (u16*)alloc(128 * 256 * 2);
    u16* ew2t  = (u16*)alloc(128 * 128 * 2);
    u16* gwt   = (u16*)alloc(128 * 128 * 2);
    u16* wqkvt = (u16*)alloc(2 * 384 * 128 * 2);
    float* bqkv = (float*)alloc(2 * 384 * 4);
    u16* wot   = (u16*)alloc(2 * 128 * 128 * 2);
    u16* w1t   = (u16*)alloc(2 * 2048 * 128 * 2);
    u16* w2t   = (u16*)alloc(2 * 128 * 2048 * 2);
    u16* h1b   = (u16*)alloc(4096 * 128 * 2);
    u16* hb    = (u16*)alloc(4096 * 128 * 2);
    float* hh  = (float*)alloc(4096 * 128 * 4);
    float* ansrc = (float*)alloc(4096 * 2 * 4);
    float* andst = (float*)alloc(4096 * 2 * 4);
    int* counts    = (int*)alloc(4096 * 4);
    int* row_start = (int*)alloc(4097 * 4);
    int* cursor    = (int*)alloc(4096 * 4);
    int* csr_src   = (int*)alloc((size_t)E * 4);
    float* y32 = (float*)alloc(4096 * 128 * 4);
    u16* yb    = (u16*)alloc(4096 * 128 * 2);
    u16* qkvb  = (u16*)alloc((size_t)4096 * 256 * 2);   // Q,K only (pitch 256)
    u16* vtb   = (u16*)alloc(4096 * 128 * 2);           // V transposed [128][4096]
    u16* attnb = (u16*)alloc(4096 * 128 * 2);
    float* po  = (float*)alloc((size_t)64 * 4 * 8 * 64 * 32 * 4);
    float* pm  = (float*)alloc(64 * 4 * 8 * 64 * 4);
    float* pl  = (float*)alloc(64 * 4 * 8 * 64 * 4);
    float* proj32 = (float*)alloc(4096 * 128 * 4);
    u16* ff1b  = (u16*)alloc((size_t)4096 * 2048 * 2);
    float* ff2part = (float*)alloc((size_t)8 * 4096 * 128 * 4);

    // ---- prep ----
    prep_kernel<<<433, 256, 0, stream>>>(x, ew1, ew2, gw, wq, wk, wv, wo, w1, w2,
                                         bq, bk, bv,
                                         xb, ew1t, ew2t, gwt, wqkvt, bqkv, wot, w1t, w2t);

    // ---- encoder MLP ----
    gemm_bf16<<<dim3(64, 2), 256, 0, stream>>>(xb, ew1t, eb1, nullptr, h1b, nullptr, nullptr, 4096, 128, 256, 1, 256, 128);
    gemm_bf16<<<dim3(64, 2), 256, 0, stream>>>(h1b, ew2t, eb2, nullptr, hb, nullptr, nullptr, 4096, 128, 128, 0, 128, 128);

    // ---- GAT ----
    gemm_bf16<<<dim3(64, 2), 256, 0, stream>>>(hb, gwt, nullptr, hh, nullptr, nullptr, nullptr, 4096, 128, 128, 0, 128, 128);
    gat_prep<<<4096, 128, 0, stream>>>(hh, gasrc, gadst, ansrc, andst);
    hipMemsetAsync(counts, 0, 4096 * sizeof(int), stream);
    count_edges<<<(E + 255) / 256, 256, 0, stream>>>(edst, counts, E);
    scan_kernel<<<1, 1024, 0, stream>>>(counts, row_start, cursor);
    scatter_edges<<<(E + 255) / 256, 256, 0, stream>>>(esrc, edst, cursor, csr_src, E);
    gat_aggregate<<<4096, 128, 0, stream>>>(row_start, csr_src, ansrc, andst, hh, gbias, y32, yb);

    // ---- transformer layers ----
    for (int l = 0; l < 2; l++) {
        gemm_bf16<<<dim3(64, 6), 256, 0, stream>>>(yb, wqkvt + l * 49152, bqkv + l * 384, nullptr, qkvb, nullptr, vtb, 4096, 384, 128, 0, 128, 256);
        flash_attn_part<<<dim3(64, 4, 8), 256, 0, stream>>>(qkvb, qkvb + 128, vtb, po, pm, pl);
        attn_combine<<<dim3(64, 4), 256, 0, stream>>>(po, pm, pl, attnb);
        gemm_bf16<<<dim3(64, 2), 256, 0, stream>>>(attnb, wot + l * 16384, bo + l * 128, proj32, nullptr, nullptr, nullptr, 4096, 128, 128, 0, 128, 128);
        add_ln<<<4096, 128, 0, stream>>>(y32, proj32, ln1g + l * 128, ln1b + l * 128, y32, yb);
        gemm_bf16<<<dim3(64, 32), 256, 0, stream>>>(yb, w1t + (size_t)l * 262144, b1 + l * 2048, nullptr, ff1b, nullptr, nullptr, 4096, 2048, 128, 1, 128, 2048);
        gemm_bf16<<<dim3(64, 2, 8), 256, 0, stream>>>(ff1b, w2t + (size_t)l * 262144, nullptr, nullptr, nullptr, ff2part, nullptr, 4096, 128, 2048, 0, 256, 128);
        float* outp = (l == 1) ? (float*)d_out : y32;
        add_ln8<<<4096, 128, 0, stream>>>(y32, ff2part, b2 + l * 128, ln2g + l * 128, ln2b + l * 128, outp, yb);
    }
}